// Round 5
// baseline (410.543 us; speedup 1.0000x reference)
//
#include <hip/hip_runtime.h>

#define HIDDEN 128
#define SCAN_CHUNK 256

// ---------------------------------------------------------------------------
// CSR build step 1: degree histogram over dst
// ---------------------------------------------------------------------------
__global__ __launch_bounds__(256) void hist_kernel(const int* __restrict__ dst,
                                                   int* __restrict__ deg, int E) {
  int e = blockIdx.x * blockDim.x + threadIdx.x;
  if (e < E) atomicAdd(&deg[dst[e]], 1);
}

// ---------------------------------------------------------------------------
// CSR scan phase A: per-block chunk sums (chunk = 256 elements, 1/thread)
// ---------------------------------------------------------------------------
__global__ __launch_bounds__(256) void scan_partial_kernel(
    const int* __restrict__ deg, int* __restrict__ partial, int N) {
  __shared__ int red[256];
  const int t = threadIdx.x;
  const int idx = blockIdx.x * SCAN_CHUNK + t;
  red[t] = (idx < N) ? deg[idx] : 0;
  __syncthreads();
#pragma unroll
  for (int off = 128; off; off >>= 1) {
    if (t < off) red[t] += red[t + off];
    __syncthreads();
  }
  if (t == 0) partial[blockIdx.x] = red[0];
}

// ---------------------------------------------------------------------------
// CSR scan phase B: one block scans the (<=256) block partials -> exclusive
// block offsets.
// ---------------------------------------------------------------------------
__global__ __launch_bounds__(256) void scan_offsets_kernel(
    const int* __restrict__ partial, int* __restrict__ blockOff, int nBlocks) {
  __shared__ int sums[256];
  const int t = threadIdx.x;
  const int p = (t < nBlocks) ? partial[t] : 0;
  sums[t] = p;
  __syncthreads();
#pragma unroll
  for (int off = 1; off < 256; off <<= 1) {
    int v = (t >= off) ? sums[t - off] : 0;
    __syncthreads();
    sums[t] += v;
    __syncthreads();
  }
  blockOff[t] = sums[t] - p;  // exclusive
}

// ---------------------------------------------------------------------------
// CSR scan phase C: per-block exclusive scan of its chunk + block offset;
// writes rowptr AND cursor.
// ---------------------------------------------------------------------------
__global__ __launch_bounds__(256) void scan_final_kernel(
    const int* __restrict__ deg, const int* __restrict__ blockOff,
    int* __restrict__ rowptr, int* __restrict__ cursor, int N) {
  __shared__ int sh[256];
  const int t = threadIdx.x;
  const int idx = blockIdx.x * SCAN_CHUNK + t;
  const int v = (idx < N) ? deg[idx] : 0;
  sh[t] = v;
  __syncthreads();
#pragma unroll
  for (int off = 1; off < 256; off <<= 1) {
    int u = (t >= off) ? sh[t - off] : 0;
    __syncthreads();
    sh[t] += u;
    __syncthreads();
  }
  const int excl = sh[t] - v + blockOff[blockIdx.x];
  if (idx < N) {
    rowptr[idx] = excl;
    cursor[idx] = excl;
    if (idx == N - 1) rowptr[N] = excl + v;
  }
}

// ---------------------------------------------------------------------------
// CSR build step 3: fill column (src) lists using per-node cursors
// ---------------------------------------------------------------------------
__global__ __launch_bounds__(256) void fill_kernel(const int* __restrict__ src,
                                                   const int* __restrict__ dst,
                                                   int* __restrict__ cursor,
                                                   int* __restrict__ col, int E) {
  int e = blockIdx.x * blockDim.x + threadIdx.x;
  if (e >= E) return;
  int pos = atomicAdd(&cursor[dst[e]], 1);
  col[pos] = src[e];
}

// ---------------------------------------------------------------------------
// Aggregation as GATHER: out[i,:] = x[i,:] + sum_{e} x[col[e],:]
// One 64-lane wave per node; each lane owns a float2 column slice.
// Beyond-L2 BW bound (~3.6 TB/s, R3 profile) — structure kept.
// ---------------------------------------------------------------------------
__global__ __launch_bounds__(256) void aggregate_kernel(
    const float* __restrict__ x, const int* __restrict__ rowptr,
    const int* __restrict__ col, float* __restrict__ out, int N) {
  int wid = (int)((blockIdx.x * (size_t)blockDim.x + threadIdx.x) >> 6);
  int lane = threadIdx.x & 63;
  if (wid >= N) return;
  const int s = rowptr[wid];
  const int e = rowptr[wid + 1];
  const int off = lane * 2;
  float2 acc = *(const float2*)(x + (size_t)wid * HIDDEN + off);
  int i = s;
  for (; i + 3 < e; i += 4) {
    int c0 = col[i], c1 = col[i + 1], c2 = col[i + 2], c3 = col[i + 3];
    float2 v0 = *(const float2*)(x + (size_t)c0 * HIDDEN + off);
    float2 v1 = *(const float2*)(x + (size_t)c1 * HIDDEN + off);
    float2 v2 = *(const float2*)(x + (size_t)c2 * HIDDEN + off);
    float2 v3 = *(const float2*)(x + (size_t)c3 * HIDDEN + off);
    acc.x += v0.x + v1.x + v2.x + v3.x;
    acc.y += v0.y + v1.y + v2.y + v3.y;
  }
  for (; i < e; ++i) {
    int c = col[i];
    float2 v = *(const float2*)(x + (size_t)c * HIDDEN + off);
    acc.x += v.x;
    acc.y += v.y;
  }
  *(float2*)(out + (size_t)wid * HIDDEN + off) = acc;
}

// ---------------------------------------------------------------------------
// One GEMM pass: acc[8][4] += xs[rows ty*8..ty*8+7][:] @ W[:, tx*4..tx*4+3].
// Weights read directly from global (coalesced 512 B rows, L1/L2-resident;
// only 64 KB per matrix) with a 1-deep rotating prefetch. No barriers.
// ---------------------------------------------------------------------------
__device__ __forceinline__ void gemm_pass(const float (*xs)[132],
                                          const float* __restrict__ Wp,
                                          int ty, float acc[8][4]) {
  float4 w[4];
#pragma unroll
  for (int kk = 0; kk < 4; ++kk)
    w[kk] = *(const float4*)(Wp + (size_t)kk * HIDDEN);
#pragma unroll 1
  for (int k = 0; k < HIDDEN; k += 4) {
    float4 wn[4];
    const int kn = (k + 4) & (HIDDEN - 1);  // last iter wraps to row 0 (cheap, in-bounds)
#pragma unroll
    for (int kk = 0; kk < 4; ++kk)
      wn[kk] = *(const float4*)(Wp + (size_t)(kn + kk) * HIDDEN);
#pragma unroll
    for (int i = 0; i < 8; ++i) {
      float4 a4 = *(const float4*)&xs[ty * 8 + i][k];
      acc[i][0] += a4.x * w[0].x + a4.y * w[1].x + a4.z * w[2].x + a4.w * w[3].x;
      acc[i][1] += a4.x * w[0].y + a4.y * w[1].y + a4.z * w[2].y + a4.w * w[3].y;
      acc[i][2] += a4.x * w[0].z + a4.y * w[1].z + a4.z * w[2].z + a4.w * w[3].z;
      acc[i][3] += a4.x * w[0].w + a4.y * w[1].w + a4.z * w[2].w + a4.w * w[3].w;
    }
#pragma unroll
    for (int kk = 0; kk < 4; ++kk) w[kk] = wn[kk];
  }
}

// ---------------------------------------------------------------------------
// Fused MLP: h2 = relu( relu(A@W1+b1) @ W2 + b2 ) for a 64-row tile.
// h1 lives only in LDS (xs reused). If doReadout: out[m] = h2[m,:]·Wr + br;
// else h2 -> Cout. Thread map: tx=t&31 owns cols tx*4.., ty=t>>5 owns rows
// ty*8+i. LDS 33.8 KB -> 4 blocks/CU, 16 waves/CU.
// ---------------------------------------------------------------------------
__global__ __launch_bounds__(256, 4) void mlp_kernel(
    const float* __restrict__ A, const float* __restrict__ W1,
    const float* __restrict__ b1, const float* __restrict__ W2,
    const float* __restrict__ b2, float* __restrict__ Cout,
    const float* __restrict__ Wr, const float* __restrict__ br,
    float* __restrict__ outv, int M, int doReadout) {
  __shared__ float xs[64][132];
  const int t = threadIdx.x;
  const int tx = t & 31;
  const int ty = t >> 5;
  const int mBase = blockIdx.x * 64;

  // stage A tile (64 x 128), zero-pad rows past M
#pragma unroll
  for (int i = 0; i < 8; ++i) {
    int idx = t + i * 256;     // 0..2047
    int r = idx >> 5;          // 0..63
    int c = (idx & 31) * 4;    // 0..124
    int gm = mBase + r;
    float4 v = make_float4(0.f, 0.f, 0.f, 0.f);
    if (gm < M) v = *(const float4*)(A + (size_t)gm * HIDDEN + c);
    *(float4*)&xs[r][c] = v;
  }
  __syncthreads();

  float acc[8][4];
#pragma unroll
  for (int i = 0; i < 8; ++i)
#pragma unroll
    for (int j = 0; j < 4; ++j) acc[i][j] = 0.f;

  // MLP1
  gemm_pass(xs, W1 + tx * 4, ty, acc);

  __syncthreads();  // all xs reads done before h1 overwrite
  float4 b1v = *(const float4*)(b1 + tx * 4);
#pragma unroll
  for (int i = 0; i < 8; ++i) {
    float4 h;
    h.x = fmaxf(acc[i][0] + b1v.x, 0.f);
    h.y = fmaxf(acc[i][1] + b1v.y, 0.f);
    h.z = fmaxf(acc[i][2] + b1v.z, 0.f);
    h.w = fmaxf(acc[i][3] + b1v.w, 0.f);
    *(float4*)&xs[ty * 8 + i][tx * 4] = h;
    acc[i][0] = acc[i][1] = acc[i][2] = acc[i][3] = 0.f;
  }
  __syncthreads();

  // MLP2
  gemm_pass(xs, W2 + tx * 4, ty, acc);

  float4 b2v = *(const float4*)(b2 + tx * 4);
  if (!doReadout) {
#pragma unroll
    for (int i = 0; i < 8; ++i) {
      int gm = mBase + ty * 8 + i;
      if (gm >= M) continue;
      float4 o;
      o.x = fmaxf(acc[i][0] + b2v.x, 0.f);
      o.y = fmaxf(acc[i][1] + b2v.y, 0.f);
      o.z = fmaxf(acc[i][2] + b2v.z, 0.f);
      o.w = fmaxf(acc[i][3] + b2v.w, 0.f);
      *(float4*)(Cout + (size_t)gm * HIDDEN + tx * 4) = o;
    }
  } else {
    float4 wr = *(const float4*)(Wr + tx * 4);
    float brv = br[0];
#pragma unroll
    for (int i = 0; i < 8; ++i) {
      float h0 = fmaxf(acc[i][0] + b2v.x, 0.f);
      float h1 = fmaxf(acc[i][1] + b2v.y, 0.f);
      float h2 = fmaxf(acc[i][2] + b2v.z, 0.f);
      float h3 = fmaxf(acc[i][3] + b2v.w, 0.f);
      float p = h0 * wr.x + h1 * wr.y + h2 * wr.z + h3 * wr.w;
      // reduce across the 32 tx lanes (xor<32 stays within the half-wave)
      p += __shfl_xor(p, 16);
      p += __shfl_xor(p, 8);
      p += __shfl_xor(p, 4);
      p += __shfl_xor(p, 2);
      p += __shfl_xor(p, 1);
      int gm = mBase + ty * 8 + i;
      if (tx == 0 && gm < M) outv[gm] = p + brv;
    }
  }
}

extern "C" void kernel_launch(void* const* d_in, const int* in_sizes, int n_in,
                              void* d_out, int out_size, void* d_ws,
                              size_t ws_size, hipStream_t stream) {
  const float* x = (const float*)d_in[0];
  const int* ei = (const int*)d_in[1];
  const float* W1_0 = (const float*)d_in[2];
  const float* b1_0 = (const float*)d_in[3];
  const float* W2_0 = (const float*)d_in[4];
  const float* b2_0 = (const float*)d_in[5];
  const float* W1_1 = (const float*)d_in[6];
  const float* b1_1 = (const float*)d_in[7];
  const float* W2_1 = (const float*)d_in[8];
  const float* b2_1 = (const float*)d_in[9];
  const float* Wr = (const float*)d_in[10];
  const float* br = (const float*)d_in[11];

  const int M = in_sizes[0] / HIDDEN;  // 50000 nodes
  const int E = in_sizes[1] / 2;       // 800000 edges
  const int* src = ei;
  const int* dst = ei + E;

  // workspace layout
  float* A = (float*)d_ws;                   // [M,128]
  float* B = A + (size_t)M * HIDDEN;         // [M,128]
  int* deg = (int*)(B + (size_t)M * HIDDEN); // [M]
  int* rowptr = deg + M;                     // [M+1]
  int* cursor = rowptr + M + 1;              // [M]
  int* col = cursor + M;                     // [E]
  int* partial = col + E;                    // [256]
  int* blockOff = partial + 256;             // [256]

  const int aggBlocks = (int)(((size_t)M * 64 + 255) / 256);
  const int scanBlocks = (M + SCAN_CHUNK - 1) / SCAN_CHUNK;
  const int mlpBlocks = (M + 63) / 64;
  float* out = (float*)d_out;

  // ---- build CSR (dst -> list of src), reused by both layers
  hipMemsetAsync(deg, 0, (size_t)M * sizeof(int), stream);
  hist_kernel<<<(E + 255) / 256, 256, 0, stream>>>(dst, deg, E);
  scan_partial_kernel<<<scanBlocks, 256, 0, stream>>>(deg, partial, M);
  scan_offsets_kernel<<<1, 256, 0, stream>>>(partial, blockOff, scanBlocks);
  scan_final_kernel<<<scanBlocks, 256, 0, stream>>>(deg, blockOff, rowptr,
                                                    cursor, M);
  fill_kernel<<<(E + 255) / 256, 256, 0, stream>>>(src, dst, cursor, col, E);

  // ---- layer 0: agg -> fused MLP -> B
  aggregate_kernel<<<aggBlocks, 256, 0, stream>>>(x, rowptr, col, A, M);
  mlp_kernel<<<mlpBlocks, 256, 0, stream>>>(A, W1_0, b1_0, W2_0, b2_0, B,
                                            nullptr, nullptr, nullptr, M, 0);

  // ---- layer 1: agg -> fused MLP + readout -> out
  aggregate_kernel<<<aggBlocks, 256, 0, stream>>>(B, rowptr, col, A, M);
  mlp_kernel<<<mlpBlocks, 256, 0, stream>>>(A, W1_1, b1_1, W2_1, b2_1, nullptr,
                                            Wr, br, out, M, 1);
}